// Round 3
// baseline (1177.427 us; speedup 1.0000x reference)
//
#include <hip/hip_runtime.h>

#define DEV __device__ __forceinline__
typedef unsigned int u32;
typedef unsigned short u16;
typedef __attribute__((ext_vector_type(8))) _Float16 f16x8;
typedef __attribute__((ext_vector_type(4))) float f32x4;

#define MFMA16(a,b,c) __builtin_amdgcn_mfma_f32_16x16x32_f16(a,b,c,0,0,0)

DEV u16 f2h(float f){ _Float16 h=(_Float16)f; return __builtin_bit_cast(u16,h); }

DEV void gload16(const void* g, void* l){
  __builtin_amdgcn_global_load_lds((const __attribute__((address_space(1))) void*)g,
                                   (__attribute__((address_space(3))) void*)l, 16, 0, 0);
}

// ---------------- prep kernels ----------------

// fp32 -> f16 (RNE), same layout
__global__ void k_cvt(const float* __restrict__ in, u16* __restrict__ out){
  size_t i=((size_t)blockIdx.x*256+threadIdx.x)*4;
  float4 v=*(const float4*)(in+i);
  uint2 hh; hh.x=(u32)f2h(v.x)|((u32)f2h(v.y)<<16); hh.y=(u32)f2h(v.z)|((u32)f2h(v.w)<<16);
  *(uint2*)(out+i)=hh;
}

// W [K][N] fp32 -> W^T [N][K] f16 (LDS-tiled transpose)
__global__ void k_trans(const float* __restrict__ W, u16* __restrict__ outT){
  __shared__ float t[64][65];
  const int tid=threadIdx.x;
  const int kb=blockIdx.y*64, nb=blockIdx.x*64;
  for(int p=0;p<4;p++){
    int r=(tid>>4)+p*16, c=(tid&15)*4;
    float4 v=*(const float4*)(W+(size_t)(kb+r)*4096+nb+c);
    t[r][c]=v.x;t[r][c+1]=v.y;t[r][c+2]=v.z;t[r][c+3]=v.w;
  }
  __syncthreads();
  for(int p=0;p<4;p++){
    int orow=(tid>>4)+p*16, oc=(tid&15)*4;
    u16 hs[4];
    for(int j=0;j<4;j++) hs[j]=f2h(t[oc+j][orow]);
    uint2 uh; uh.x=(u32)hs[0]|((u32)hs[1]<<16); uh.y=(u32)hs[2]|((u32)hs[3]<<16);
    *(uint2*)(outT+(size_t)(nb+orow)*4096+kb+oc)=uh;
  }
}

// RoPE tables: [2048][64] cos, sin
__global__ void k_rope_tab(float* __restrict__ cosT, float* __restrict__ sinT){
  int i=blockIdx.x*256+threadIdx.x;           // 131072 total
  int s=i>>6, f=i&63;
  float inv=powf(10000.f, -(float)(2*f)/128.f);
  float ang=(float)s*inv;
  cosT[i]=cosf(ang); sinT[i]=sinf(ang);
}

// ---------------- f16 single-product GEMM (m97 structure) ----------------
// C[m][n] = sum_k A[m][k]*BT[n][k], 4096^3, A/BT f16, fp32 accum.
// EPI 1: RoPE + f16 store into [B,H,S,HD] (q/k).  EPI 2: f16 store row-major (v^T).
// EPI 3: fp32 store (final output).
template<int EPI>
__global__ __launch_bounds__(256,2) void k_gemm(
    const u16* __restrict__ A, const u16* __restrict__ B,
    float* __restrict__ outF, u16* __restrict__ outH,
    const float* __restrict__ cosT, const float* __restrict__ sinT)
{
  __shared__ u16 lds[2][4096];   // A, B : 128x32 f16 each
  const int tid=threadIdx.x, lane=tid&63, w=tid>>6;
  const int m0=blockIdx.y*128, n0=blockIdx.x*128;
  const int wm=(w>>1)*64, wn=(w&1)*64;
  const f32x4 zero4={0.f,0.f,0.f,0.f};
  f32x4 acc[4][4];
  for(int m=0;m<4;m++)for(int n=0;n<4;n++)acc[m][n]=zero4;
  const int srow=lane>>2, soff=(lane&3)*8;
  for(int k0=0;k0<4096;k0+=32){
    for(int q8=w;q8<8;q8+=4){
      int r=q8*16+srow;
      gload16(A+(size_t)(m0+r)*4096+k0+soff,(char*)&lds[0][0]+q8*1024);
      gload16(B+(size_t)(n0+r)*4096+k0+soff,(char*)&lds[1][0]+q8*1024);
    }
    __syncthreads();
    const int fr=lane&15, fo=(lane>>4)*8;
    f16x8 ah[4],bh[4];
    for(int m=0;m<4;m++) ah[m]=*(const f16x8*)&lds[0][(wm+m*16+fr)*32+fo];
    for(int n=0;n<4;n++) bh[n]=*(const f16x8*)&lds[1][(wn+n*16+fr)*32+fo];
    for(int m=0;m<4;m++)for(int n=0;n<4;n++)
      acc[m][n]=MFMA16(ah[m],bh[n],acc[m][n]);
    __syncthreads();
  }
  for(int m=0;m<4;m++)for(int n=0;n<4;n++){
    int col=n0+wn+n*16+(lane&15);
    for(int r=0;r<4;r++){
      int row=m0+wm+m*16+(lane>>4)*4+r;
      float v=acc[m][n][r];
      if constexpr(EPI==1){
        int b=row>>11, s=row&2047, hd=col&127, hh=col>>7;
        float part=__shfl_xor(v,1);
        int fi=hd>>1;
        float cs=cosT[s*64+fi], sn=sinT[s*64+fi];
        float o=(hd&1)?(part*sn+v*cs):(v*cs-part*sn);
        size_t addr=((size_t)(b*32+hh)*2048+s)*128+hd;
        outH[addr]=f2h(o);
      } else if constexpr(EPI==2){
        outH[(size_t)row*4096+col]=f2h(v);
      } else {
        outF[(size_t)row*4096+col]=v;
      }
    }
  }
}

// ---------------- flash attention (f16 single-product) ----------------
// grid (S/64, H, B), 256 threads, LPT order (big q-blocks first).
// Wave w owns q rows [q0+16w, q0+16w+16).
// Q/K: [B,H,S,HD] f16.  V^T: [4096=d][4096=b*2048+s] f16.
// Swapped QK^T (mfma(K,Q) -> S^T, q=lane&15). XOR-swizzled LDS everywhere.
__global__ __launch_bounds__(256,4) void k_attn(
    const u16* __restrict__ Q, const u16* __restrict__ K,
    const u16* __restrict__ VT, u16* __restrict__ Oat)
{
  __shared__ u16 kv[8192];       // time-shared: K [64][128] then V^T [128][64]
  __shared__ u16 pbuf[4][1024];  // per-wave P [16 q][64 kv]
  const int tid=threadIdx.x, lane=tid&63, w=tid>>6;
  const int q0=(31-(int)blockIdx.x)*64;          // LPT: longest blocks launch first
  const int hh=blockIdx.y, b=blockIdx.z;
  const size_t headoff=((size_t)(b*32+hh))*2048*128;
  f16x8 qh[4];
  {
    int qr=q0+w*16+(lane&15);
    for(int c=0;c<4;c++)
      qh[c]=*(const f16x8*)(Q+headoff+(size_t)qr*128+(lane>>4)*8+32*c);
  }
  const f32x4 zero4={0.f,0.f,0.f,0.f};
  f32x4 O[8]; for(int i=0;i<8;i++)O[i]=zero4;
  float m_run=-__builtin_inff(), l_run=0.f;
  const int nt=q0/64+1;
  const int qg=q0+w*16+(lane&15);
  const float scale=0.08838834764831845f;  // 1/sqrt(128)
  for(int t=0;t<nt;t++){
    const int kv0=t*64;
    // stage K: LDS [64][128] f16 with byte^=((row&7)<<4) swizzle via pre-swizzled src
    for(int ch=w*4;ch<w*4+4;++ch){
      int p=ch*1024+lane*16;
      int row=p>>8, slot=(p>>4)&15, ss=slot^(row&7);
      gload16(K+headoff+(size_t)(kv0+row)*128+ss*8,(char*)kv+ch*1024);
    }
    __syncthreads();
    // QK^T: S^T[kv][q]
    f32x4 st[4]; for(int m=0;m<4;m++)st[m]=zero4;
    for(int c=0;c<4;c++){
      for(int m=0;m<4;m++){
        int row=m*16+(lane&15);
        int off=(((lane>>4)*16)+64*c)^((row&7)<<4);
        f16x8 k8=*(const f16x8*)((const char*)kv+row*256+off);
        st[m]=MFMA16(k8,qh[c],st[m]);
      }
    }
    __syncthreads();
    // stage V^T: LDS [128][64] f16, swizzled; overlaps with softmax below
    for(int ch=w*4;ch<w*4+4;++ch){
      int p=ch*1024+lane*16;
      int row=p>>7, slot=(p>>4)&7, ps=slot^(row&7);
      gload16(VT+(size_t)(hh*128+row)*4096+(size_t)b*2048+kv0+ps*8,(char*)kv+ch*1024);
    }
    // online softmax (q = lane&15, kv spread over 4 lane-groups x 4 regs)
    float pm=-__builtin_inff();
    for(int m=0;m<4;m++)for(int r=0;r<4;r++){
      float sv=st[m][r]*scale;
      int kvi=kv0+m*16+(lane>>4)*4+r;
      if(kvi>qg)sv=-__builtin_inff();
      st[m][r]=sv;
      pm=fmaxf(pm,sv);
    }
    pm=fmaxf(pm,__shfl_xor(pm,16));
    pm=fmaxf(pm,__shfl_xor(pm,32));
    float m_new=fmaxf(m_run,pm);
    float corr=__expf(m_run-m_new);
    float psum=0.f;
    const int q=lane&15;
    for(int m=0;m<4;m++){
      u16 ph[4];
      for(int r=0;r<4;r++){
        float p=__expf(st[m][r]-m_new);
        psum+=p;
        ph[r]=f2h(p);
      }
      int off=((m*32)+((lane>>4)*8))^((q&7)<<4);
      uint2 uh; uh.x=(u32)ph[0]|((u32)ph[1]<<16); uh.y=(u32)ph[2]|((u32)ph[3]<<16);
      *(uint2*)((char*)&pbuf[w][0]+q*128+off)=uh;
    }
    psum+=__shfl_xor(psum,16);
    psum+=__shfl_xor(psum,32);
    l_run=l_run*corr+psum;
    m_run=m_new;
    float cb[4];
    for(int r=0;r<4;r++)cb[r]=__shfl(corr,(lane>>4)*4+r);
    for(int nb=0;nb<8;nb++)for(int r=0;r<4;r++)O[nb][r]*=cb[r];
    __syncthreads();
    // PV: O[q][d] += P[q][kv] @ V[kv][d]
    for(int c2=0;c2<2;c2++){
      int offp=(((lane>>4)*16)+64*c2)^((q&7)<<4);
      f16x8 pa=*(const f16x8*)((const char*)&pbuf[w][0]+q*128+offp);
      for(int nb=0;nb<8;nb++){
        int vrow=nb*16+(lane&15);
        int voff=(((lane>>4)*16)+64*c2)^((vrow&7)<<4);
        f16x8 v8=*(const f16x8*)((const char*)kv+vrow*128+voff);
        O[nb]=MFMA16(pa,v8,O[nb]);
      }
    }
    __syncthreads();
  }
  float lb[4];
  for(int r=0;r<4;r++)lb[r]=__shfl(l_run,(lane>>4)*4+r);
  for(int nb=0;nb<8;nb++){
    int col=hh*128+nb*16+(lane&15);
    for(int r=0;r<4;r++){
      float o=O[nb][r]/lb[r];
      size_t rowg=(size_t)b*2048+q0+w*16+(lane>>4)*4+r;
      Oat[rowg*4096+col]=f2h(o);
    }
  }
}

// ---------------- launch ----------------
extern "C" void kernel_launch(void* const* d_in, const int* in_sizes, int n_in,
                              void* d_out, int out_size, void* d_ws, size_t ws_size,
                              hipStream_t stream){
  (void)in_sizes;(void)n_in;(void)out_size;
  const float* x =(const float*)d_in[0];
  const float* wq=(const float*)d_in[1];
  const float* wk=(const float*)d_in[2];
  const float* wv=(const float*)d_in[3];
  const float* wo=(const float*)d_in[4];
  const size_t NELEM=(size_t)4096*4096;
  const size_t MAT=NELEM*sizeof(u16);                 // 32 MiB
  const size_t TAB=(size_t)2048*64*sizeof(float);     // 0.5 MiB
  const size_t need=5*MAT+2*TAB;                      // ~161 MB
  if(ws_size<need)return;
  char* ws=(char*)d_ws;
  size_t off=0;
  auto alloc=[&](size_t bytes)->char*{ char* p=ws+off; off+=bytes; return p; };
  u16* x_h =(u16*)alloc(MAT);
  u16* w_h =(u16*)alloc(MAT);      // reused for wq,wk,wv,wo (transposed)
  u16* q_h =(u16*)alloc(MAT);
  u16* k_h =(u16*)alloc(MAT);
  u16* vT_h=(u16*)alloc(MAT);
  float* cosT=(float*)alloc(TAB);
  float* sinT=(float*)alloc(TAB);
  u16* at_h=x_h;                                      // x buffer dead after V gemm

  dim3 tg(64,64), gg(32,32), ga(32,32,2);
  k_rope_tab<<<512,256,0,stream>>>(cosT,sinT);
  k_cvt<<<(u32)(NELEM/1024),256,0,stream>>>(x,x_h);
  // q = rope(x@wq) -> [B,H,S,HD]
  k_trans<<<tg,256,0,stream>>>(wq,w_h);
  k_gemm<1><<<gg,256,0,stream>>>(x_h,w_h,nullptr,q_h,cosT,sinT);
  // k = rope(x@wk)
  k_trans<<<tg,256,0,stream>>>(wk,w_h);
  k_gemm<1><<<gg,256,0,stream>>>(x_h,w_h,nullptr,k_h,cosT,sinT);
  // v^T = wv^T @ x^T  (A=wvT, BT=x) -> [d][b*S+s]
  k_trans<<<tg,256,0,stream>>>(wv,w_h);
  k_gemm<2><<<gg,256,0,stream>>>(w_h,x_h,nullptr,vT_h,nullptr,nullptr);
  // attention -> at (aliases x)
  k_attn<<<ga,256,0,stream>>>(q_h,k_h,vT_h,at_h);
  // out = attn @ wo (fp32)
  k_trans<<<tg,256,0,stream>>>(wo,w_h);
  k_gemm<3><<<gg,256,0,stream>>>(at_h,w_h,(float*)d_out,nullptr,nullptr,nullptr);
}